// Round 14
// baseline (368.495 us; speedup 1.0000x reference)
//
#include <hip/hip_runtime.h>
#include <hip/hip_bf16.h>
#include <math.h>

#define B_   32
#define T_   4096
#define D_   1024
#define H_   256
#define KTH  2048           // threshold_index = int(T*0.5)
#define SC   32             // pv chunks per batch
#define BKL  64             // K per tile (8-phase kernel)
#define NKT  (D_/BKL)       // 16 K-tiles
#define EPSB 4.0e-3f        // refinement band half-width (~8 sigma of bf16 e-error)
#define MAXBAND 256
#define RB   4              // refine rows per block-group

typedef __attribute__((ext_vector_type(8))) short short8;
typedef __attribute__((ext_vector_type(4))) float f32x4;

#define FENCE0() asm volatile("s_waitcnt vmcnt(0) lgkmcnt(0)" ::: "memory")
#define BARRIER() __builtin_amdgcn_s_barrier()
#define GLL(src, dst) __builtin_amdgcn_global_load_lds( \
    (const __attribute__((address_space(1))) unsigned int*)(src), \
    (__attribute__((address_space(3))) unsigned int*)(dst), 16, 0, 0)

// ---------- helpers ----------
__device__ inline unsigned f2s(float f) {
    unsigned u = __float_as_uint(f);
    return (u & 0x80000000u) ? ~u : (u | 0x80000000u);
}
__device__ inline float s2f(unsigned s) {
    unsigned x = (s & 0x80000000u) ? (s & 0x7fffffffu) : ~s;
    return __uint_as_float(x);
}
__device__ inline unsigned f2bf_rne(float f) {      // round-to-nearest-even bf16
    unsigned u = __float_as_uint(f);
    return (u + 0x7FFFu + ((u >> 16) & 1u)) >> 16;
}
__device__ inline unsigned pk2(float a, float b) {
    return f2bf_rne(a) | (f2bf_rne(b) << 16);
}
__device__ inline int block_sum_i(int v, int* sb, int tid) {
    #pragma unroll
    for (int o = 32; o; o >>= 1) v += __shfl_down(v, o);
    __syncthreads();
    if ((tid & 63) == 0) sb[tid >> 6] = v;
    __syncthreads();
    return sb[0] + sb[1] + sb[2] + sb[3];
}
__device__ inline float block_max_f(float v, float* sb, int tid) {
    #pragma unroll
    for (int o = 32; o; o >>= 1) v = fmaxf(v, __shfl_down(v, o));
    __syncthreads();
    if ((tid & 63) == 0) sb[tid >> 6] = v;
    __syncthreads();
    return fmaxf(fmaxf(sb[0], sb[1]), fmaxf(sb[2], sb[3]));
}
__device__ inline float block_sum_f(float v, float* sb, int tid) {
    #pragma unroll
    for (int o = 32; o; o >>= 1) v += __shfl_down(v, o);
    __syncthreads();
    if ((tid & 63) == 0) sb[tid >> 6] = v;
    __syncthreads();
    return sb[0] + sb[1] + sb[2] + sb[3];
}

// ---------- W1 [K][N] fp32 -> W1T bf16(RNE) [N][K] ----------
__global__ __launch_bounds__(256) void k_w1t(const float* __restrict__ W1,
                                             ushort* __restrict__ Whi) {
    __shared__ float tile[32][33];
    const int kb = blockIdx.x * 32, nb = blockIdx.y * 32;
    const int tx = threadIdx.x & 31, ty = threadIdx.x >> 5;   // ty 0..7
    #pragma unroll
    for (int i = 0; i < 4; i++)
        tile[ty + 8*i][tx] = W1[(long)(kb + ty + 8*i) * H_ + nb + tx];
    __syncthreads();
    #pragma unroll
    for (int i = 0; i < 4; i++) {
        long o = (long)(nb + ty + 8*i) * D_ + kb + tx;
        Whi[o] = (ushort)f2bf_rne(tile[tx][ty + 8*i]);
    }
}

// ---------- phase 1: 8-phase (4/K-tile) m201-style MFMA GEMM -> e ----------
// Block 256 rows x 256 cols, 512 thr = 8 waves (2m x 4n), wave tile 128x64,
// acc 8x4 frags (128 regs). BK=64, NKT=16, LDS 128KB double-buffered.
// Per K-tile, 4 phases (one C-quadrant each, 16 MFMA):
//   {12 ds_read frags | staging slice | barrier | lgkmcnt(0)+sched_barrier |
//    setprio(1) 16 MFMA setprio(0) | [P4 only: vmcnt(0)] | barrier}
// Staging: P1 issues 8 A fp32 reg-loads (tile t+1), P2/P3 issue 2+2 B
// global_load_lds, P4 cvt+ds_writes A into the other buffer. vmcnt(0) only
// once per tile (P4), before the closing barrier so GLL data is
// barrier-ordered for all waves. LDS fragment-major: [slab=row>>4][kc=k>>3]
// [row&15][8] -> every frag ds_read_b128 = base + lane*16 (conflict-free).
__global__ __launch_bounds__(512, 2) void k_e_mfma(
    const float* __restrict__ x,
    const ushort* __restrict__ Whi,
    const float* __restrict__ b1, const float* __restrict__ W2,
    const float* __restrict__ b2, float* __restrict__ e_out)
{
    __shared__ ushort smem[65536];   // 128 KB: A0|A1|B0|B1, 16384 ushorts each

    const int tid  = threadIdx.x;
    const int lane = tid & 63;
    const int wv   = tid >> 6;
    const int wm   = wv >> 2, wn = wv & 3;       // 2m x 4n
    const int l15  = lane & 15, lg = lane >> 4;
    const long row0 = (long)blockIdx.x * 256;

    ushort* sA0 = smem;
    ushort* sA1 = smem + 16384;
    ushort* sB0 = smem + 32768;
    ushort* sB1 = smem + 49152;

    // A staging: thread -> row ar=tid>>1 (0..255), k-half ah=tid&1 (32 fp32)
    const int ar = tid >> 1, ah = tid & 1;
    const float* aga = x + (row0 + ar) * (long)D_ + ah * 32;
    const int awo = (ar >> 4) * 1024 + (ar & 15) * 8;   // + (ah*4+q)*128

    // B staging: 4 chunks c = tid + j*512; c -> slab=c>>7, kc=(c>>4)&7, row=c&15
    const ushort* bsrc[4]; int bdst[4];
    #pragma unroll
    for (int j = 0; j < 4; j++) {
        const int c = tid + j * 512;
        const int slab = c >> 7, kc = (c >> 4) & 7, row = c & 15;
        bsrc[j] = Whi + (long)(slab * 16 + row) * D_ + kc * 8;
        bdst[j] = c * 8;
    }

    // fragment base offsets (add (MH*4+fm)*1024 / (NH*2+fn)*1024 and kh*512)
    const int abase = wm * 8192 + lg * 128 + l15 * 8;
    const int bbase = wn * 4096 + lg * 128 + l15 * 8;

    f32x4 acc[8][4];
    #pragma unroll
    for (int i = 0; i < 8; i++)
        #pragma unroll
        for (int j = 0; j < 4; j++) acc[i][j] = (f32x4){0.f, 0.f, 0.f, 0.f};

    float4 Ra[8];

#define LOADS_A() do { if (more) { \
    _Pragma("unroll") \
    for (int q = 0; q < 8; q++) Ra[q] = *(const float4*)(aga + ko + q * 4); \
} } while (0)
#define GLL01() do { if (more) { \
    GLL(bsrc[0] + ko, sBn + bdst[0]); \
    GLL(bsrc[1] + ko, sBn + bdst[1]); \
} } while (0)
#define GLL23() do { if (more) { \
    GLL(bsrc[2] + ko, sBn + bdst[2]); \
    GLL(bsrc[3] + ko, sBn + bdst[3]); \
} } while (0)
#define AWRITE() do { if (more) { \
    _Pragma("unroll") \
    for (int q = 0; q < 4; q++) { \
        uint4 _u = make_uint4(pk2(Ra[2*q].x, Ra[2*q].y), pk2(Ra[2*q].z, Ra[2*q].w), \
                              pk2(Ra[2*q+1].x, Ra[2*q+1].y), pk2(Ra[2*q+1].z, Ra[2*q+1].w)); \
        *(uint4*)&sAn[awo + (ah * 4 + q) * 128] = _u; \
    } \
} } while (0)
#define NOOP() do {} while (0)

#define PHASE(MH, NH, STAGE_STMT, FENCE_STMT) do { \
    short8 _af[2][4], _bf[2][2]; \
    _Pragma("unroll") \
    for (int kh = 0; kh < 2; kh++) { \
        _Pragma("unroll") \
        for (int fm = 0; fm < 4; fm++) \
            _af[kh][fm] = *(const short8*)&sAc[abase + ((MH)*4 + fm) * 1024 + kh * 512]; \
        _Pragma("unroll") \
        for (int fn = 0; fn < 2; fn++) \
            _bf[kh][fn] = *(const short8*)&sBc[bbase + ((NH)*2 + fn) * 1024 + kh * 512]; \
    } \
    STAGE_STMT; \
    BARRIER(); \
    asm volatile("s_waitcnt lgkmcnt(0)" ::: "memory"); \
    __builtin_amdgcn_sched_barrier(0); \
    __builtin_amdgcn_s_setprio(1); \
    _Pragma("unroll") \
    for (int kh = 0; kh < 2; kh++) \
        _Pragma("unroll") \
        for (int fm = 0; fm < 4; fm++) \
            _Pragma("unroll") \
            for (int fn = 0; fn < 2; fn++) \
                acc[(MH)*4 + fm][(NH)*2 + fn] = __builtin_amdgcn_mfma_f32_16x16x32_bf16( \
                    _af[kh][fm], _bf[kh][fn], acc[(MH)*4 + fm][(NH)*2 + fn], 0, 0, 0); \
    __builtin_amdgcn_s_setprio(0); \
    FENCE_STMT; \
    BARRIER(); \
} while (0)

    // ----- prologue: stage tile 0 into buf0, drain, barrier -----
    {
        #pragma unroll
        for (int j = 0; j < 4; j++) GLL(bsrc[j], sB0 + bdst[j]);
        #pragma unroll
        for (int q = 0; q < 8; q++) Ra[q] = *(const float4*)(aga + q * 4);
        #pragma unroll
        for (int q = 0; q < 4; q++) {
            uint4 u = make_uint4(pk2(Ra[2*q].x, Ra[2*q].y), pk2(Ra[2*q].z, Ra[2*q].w),
                                 pk2(Ra[2*q+1].x, Ra[2*q+1].y), pk2(Ra[2*q+1].z, Ra[2*q+1].w));
            *(uint4*)&sA0[awo + (ah * 4 + q) * 128] = u;
        }
        FENCE0(); BARRIER();
    }

    // ----- main loop: 16 K-tiles x 4 phases -----
    for (int t = 0; t < NKT; ++t) {
        const ushort* sAc = (t & 1) ? sA1 : sA0;
        const ushort* sBc = (t & 1) ? sB1 : sB0;
        ushort* sAn = (t & 1) ? sA0 : sA1;
        ushort* sBn = (t & 1) ? sB0 : sB1;
        const bool more = (t + 1 < NKT);
        const int ko = (t + 1) * BKL;

        PHASE(0, 0, LOADS_A(), NOOP());
        PHASE(0, 1, GLL01(),   NOOP());
        PHASE(1, 0, GLL23(),   NOOP());
        PHASE(1, 1, AWRITE(),  FENCE0());
    }

#undef PHASE
#undef NOOP
#undef AWRITE
#undef GLL23
#undef GLL01
#undef LOADS_A

    // ----- epilogue: e partial = sum_j tanh(G+b1[j])*W2[j] -----
    // D frag: col=l15, row=lg*4+r; wave rows = wm*128 + fm*16 + lg*4 + r
    float b1v[4], w2v[4];
    #pragma unroll
    for (int fn = 0; fn < 4; fn++) {
        int j = wn * 64 + fn * 16 + l15;
        b1v[fn] = b1[j]; w2v[fn] = W2[j];
    }
    float* sRed = (float*)smem;    // [4 wn][256 rows] = 4 KB, aliases sA0 (safe: all reads done)
    #pragma unroll
    for (int fm = 0; fm < 8; fm++) {
        #pragma unroll
        for (int r = 0; r < 4; r++) {
            float s = 0.f;
            #pragma unroll
            for (int fn = 0; fn < 4; fn++)
                s += tanhf(acc[fm][fn][r] + b1v[fn]) * w2v[fn];
            s += __shfl_xor(s, 1); s += __shfl_xor(s, 2);
            s += __shfl_xor(s, 4); s += __shfl_xor(s, 8);
            if (l15 == 0) sRed[wn * 256 + wm * 128 + fm * 16 + lg * 4 + r] = s;
        }
    }
    __syncthreads();
    if (tid < 256)
        e_out[row0 + tid] = sRed[tid] + sRed[256 + tid] + sRed[512 + tid] + sRed[768 + tid] + b2[0];
}

// ---------- phase 2: rank threshold; BUILD=1 -> band list, BUILD=0 -> survivor list ----------
// thread handles 16 CONSECUTIVE t (t = tid*16+i) so compaction is t-ordered.
template<int BUILD>
__global__ __launch_bounds__(256) void k_thresh(const float* __restrict__ e,
                                                int* __restrict__ counts,
                                                int* __restrict__ list,
                                                int* __restrict__ sidx,
                                                float* __restrict__ sval,
                                                int* __restrict__ scount) {
    __shared__ int   sbi[4];
    __shared__ float sbf[4];
    __shared__ int   wsum[4];
    __shared__ int   scnt;
    const int b = blockIdx.x, tid = threadIdx.x;
    const int lane = tid & 63, wid = tid >> 6;
    const float* eb = e + (long)b * T_;
    const int t0 = tid * 16;

    float fe[16]; unsigned ue[16];
    #pragma unroll
    for (int i = 0; i < 16; i += 4) {
        float4 v = *(const float4*)(eb + t0 + i);
        fe[i] = v.x; fe[i+1] = v.y; fe[i+2] = v.z; fe[i+3] = v.w;
    }
    #pragma unroll
    for (int i = 0; i < 16; i++) ue[i] = f2s(fe[i]);

    unsigned lo = 0u, hi = 0xFFFFFFFFu;
    while (lo < hi) {
        unsigned mid = lo + ((hi - lo) >> 1);
        int c = 0;
        #pragma unroll
        for (int i = 0; i < 16; i++) c += (ue[i] <= mid) ? 1 : 0;
        int total = block_sum_i(c, sbi, tid);
        if (total >= KTH + 1) hi = mid; else lo = mid + 1;
    }
    const float thr = s2f(lo);

    if (BUILD) {
        if (tid == 0) scnt = 0;
        __syncthreads();
        #pragma unroll
        for (int i = 0; i < 16; i++) {
            if (fabsf(fe[i] - thr) <= EPSB) {
                int p = atomicAdd(&scnt, 1);
                if (p < MAXBAND) list[b * MAXBAND + p] = t0 + i;
            }
        }
        __syncthreads();
        if (tid == 0) counts[b] = scnt < MAXBAND ? scnt : MAXBAND;
    } else {
        float m = -INFINITY;
        #pragma unroll
        for (int i = 0; i < 16; i++) if (fe[i] < thr) m = fmaxf(m, fe[i]);
        m = block_max_f(m, sbf, tid);
        float s = 0.f;
        #pragma unroll
        for (int i = 0; i < 16; i++) if (fe[i] < thr) s += expf(fe[i] - m);
        s = block_sum_f(s, sbf, tid);
        const float inv = 1.0f / s;

        // deterministic t-ordered compaction: block exclusive scan of counts
        int c = 0;
        #pragma unroll
        for (int i = 0; i < 16; i++) c += (fe[i] < thr) ? 1 : 0;
        int p = c;
        #pragma unroll
        for (int o = 1; o < 64; o <<= 1) {
            int y = __shfl_up(p, o);
            if (lane >= o) p += y;
        }
        if (lane == 63) wsum[wid] = p;          // wave total
        __syncthreads();
        int base = 0;
        #pragma unroll
        for (int w = 0; w < 4; w++) base += (w < wid) ? wsum[w] : 0;
        int pos = base + p - c;                 // exclusive prefix
        #pragma unroll
        for (int i = 0; i < 16; i++) {
            if (fe[i] < thr) {
                sidx[(long)b * T_ + pos] = t0 + i;
                sval[(long)b * T_ + pos] = expf(fe[i] - m) * inv;
                pos++;
            }
        }
        if (tid == 0) scount[b] = wsum[0] + wsum[1] + wsum[2] + wsum[3];
    }
}

// ---------- phase 2.5: exact fp32 recompute of band rows, RB rows share one W1 stream ----------
__global__ __launch_bounds__(256) void k_refine(const float* __restrict__ x,
        const float* __restrict__ W1, const float* __restrict__ b1,
        const float* __restrict__ W2, const float* __restrict__ b2,
        const int* __restrict__ counts, const int* __restrict__ list,
        float* __restrict__ e) {
    const int b   = blockIdx.y;
    const int blk = blockIdx.x;            // 0..15
    const int cnt = counts[b];
    const int tid = threadIdx.x;
    __shared__ float xs[RB][D_];           // 16 KB
    __shared__ float sbf[4];

    for (int g = blk * RB; g < cnt; g += 16 * RB) {
        const int nr = min(RB, cnt - g);
        for (int j = 0; j < nr; j++) {
            const int t = list[b * MAXBAND + g + j];
            *(float4*)&xs[j][tid * 4] =
                *(const float4*)&x[((long)b * T_ + t) * D_ + tid * 4];
        }
        __syncthreads();

        float a0 = 0.f, a1 = 0.f, a2 = 0.f, a3 = 0.f;
        for (int k0 = 0; k0 < D_; k0 += 4) {
            const float w0 = W1[(long)(k0 + 0) * H_ + tid];
            const float w1v = W1[(long)(k0 + 1) * H_ + tid];
            const float w2q = W1[(long)(k0 + 2) * H_ + tid];
            const float w3 = W1[(long)(k0 + 3) * H_ + tid];
            {
                float4 xv = *(const float4*)&xs[0][k0];
                a0 = fmaf(xv.x, w0, a0); a0 = fmaf(xv.y, w1v, a0);
                a0 = fmaf(xv.z, w2q, a0); a0 = fmaf(xv.w, w3, a0);
            }
            {
                float4 xv = *(const float4*)&xs[1][k0];
                a1 = fmaf(xv.x, w0, a1); a1 = fmaf(xv.y, w1v, a1);
                a1 = fmaf(xv.z, w2q, a1); a1 = fmaf(xv.w, w3, a1);
            }
            {
                float4 xv = *(const float4*)&xs[2][k0];
                a2 = fmaf(xv.x, w0, a2); a2 = fmaf(xv.y, w1v, a2);
                a2 = fmaf(xv.z, w2q, a2); a2 = fmaf(xv.w, w3, a2);
            }
            {
                float4 xv = *(const float4*)&xs[3][k0];
                a3 = fmaf(xv.x, w0, a3); a3 = fmaf(xv.y, w1v, a3);
                a3 = fmaf(xv.z, w2q, a3); a3 = fmaf(xv.w, w3, a3);
            }
        }

        float aj[RB] = {a0, a1, a2, a3};
        for (int j = 0; j < nr; j++) {
            float v = tanhf(aj[j] + b1[tid]) * W2[tid];
            float tot = block_sum_f(v, sbf, tid);
            if (tid == 0) {
                const int t = list[b * MAXBAND + g + j];
                e[(long)b * T_ + t] = tot + b2[0];
            }
            __syncthreads();
        }
        __syncthreads();
    }
}

// ---------- phase 3: dense survivor-list PV: partial[b][c][d] ----------
__global__ __launch_bounds__(256) void k_pv(const float* __restrict__ x,
                                            const int* __restrict__ sidx,
                                            const float* __restrict__ sval,
                                            const int* __restrict__ scount,
                                            float* __restrict__ partial) {
    const int c = blockIdx.x, b = blockIdx.y, tid = threadIdx.x;
    const int cnt = scount[b];
    const int len = (cnt + SC - 1) / SC;
    const int k0 = c * len;
    const int nl = min(len, cnt - k0);
    __shared__ int   si[96];
    __shared__ float sv[96];
    if (tid < nl) {
        si[tid] = sidx[(long)b * T_ + k0 + tid];
        sv[tid] = sval[(long)b * T_ + k0 + tid];
    }
    __syncthreads();

    float4 acc = {0.f, 0.f, 0.f, 0.f};
    const float* xb = x + (long)b * T_ * D_ + tid * 4;
    for (int k = 0; k < nl; k++) {
        const float w = sv[k];
        float4 v = *(const float4*)(xb + (long)si[k] * D_);
        acc.x = fmaf(w, v.x, acc.x);
        acc.y = fmaf(w, v.y, acc.y);
        acc.z = fmaf(w, v.z, acc.z);
        acc.w = fmaf(w, v.w, acc.w);
    }
    *(float4*)&partial[(((long)b * SC) + c) * D_ + tid * 4] = acc;
}

// ---------- phase 4 ----------
__global__ __launch_bounds__(256) void k_red(const float* __restrict__ partial,
                                             float* __restrict__ out) {
    const int b = blockIdx.x, tid = threadIdx.x;
    float4 acc = {0.f, 0.f, 0.f, 0.f};
    #pragma unroll
    for (int c = 0; c < SC; c++) {
        float4 v = *(const float4*)&partial[(((long)b * SC) + c) * D_ + tid * 4];
        acc.x += v.x; acc.y += v.y; acc.z += v.z; acc.w += v.w;
    }
    *(float4*)&out[(long)b * D_ + tid * 4] = acc;
}

extern "C" void kernel_launch(void* const* d_in, const int* in_sizes, int n_in,
                              void* d_out, int out_size, void* d_ws, size_t ws_size,
                              hipStream_t stream) {
    const float* x  = (const float*)d_in[0];
    const float* W1 = (const float*)d_in[1];
    const float* b1 = (const float*)d_in[2];
    const float* W2 = (const float*)d_in[3];
    const float* b2 = (const float*)d_in[4];
    float* out = (float*)d_out;

    char* ws = (char*)d_ws;
    float* e       = (float*)ws;  ws += (size_t)B_ * T_ * 4;
    int*   sidx    = (int*)ws;    ws += (size_t)B_ * T_ * 4;
    float* sval    = (float*)ws;  ws += (size_t)B_ * T_ * 4;
    float* partial = (float*)ws;  ws += (size_t)B_ * SC * D_ * 4;
    ushort* Whi    = (ushort*)ws; ws += (size_t)H_ * D_ * 2;
    int* counts    = (int*)ws;    ws += 128;
    int* scountp   = (int*)ws;    ws += 128;
    int* list      = (int*)ws;

    k_w1t<<<dim3(D_ / 32, H_ / 32), 256, 0, stream>>>(W1, Whi);
    k_e_mfma<<<(B_ * T_) / 256, 512, 0, stream>>>(x, Whi, b1, W2, b2, e);
    k_thresh<1><<<B_, 256, 0, stream>>>(e, counts, list, sidx, sval, scountp);
    k_refine<<<dim3(16, B_), 256, 0, stream>>>(x, W1, b1, W2, b2, counts, list, e);
    k_thresh<0><<<B_, 256, 0, stream>>>(e, counts, list, sidx, sval, scountp);
    k_pv<<<dim3(SC, B_), 256, 0, stream>>>(x, sidx, sval, scountp, partial);
    k_red<<<B_, 256, 0, stream>>>(partial, out);
}